// Round 1
// baseline (162.722 us; speedup 1.0000x reference)
//
#include <hip/hip_runtime.h>

#define HH 1024
#define WW 1024
#define NB 16
#define NROWS (NB * HH)          // 16384 (b*H + y), batch rows contiguous
#define NELEM ((long long)NROWS * WW)

// One block per (b, y) row. Stage rows y-2, y, y+2 of y_pred into LDS with a
// 4-element zero halo each side (indices [0..3] and [1028..1031]); neighbor
// accesses at x +/- 2 then never wrap across rows or batch images.
__global__ __launch_bounds__(256) void closs_main(const float* __restrict__ yt,
                                                  const float* __restrict__ yp,
                                                  float* __restrict__ partial) {
    __shared__ float up[1032];
    __shared__ float ce[1032];
    __shared__ float dn[1032];

    const int r   = blockIdx.x;        // flat row index = b*H + y
    const int y   = r & (HH - 1);
    const int tid = threadIdx.x;
    const int x4  = tid << 2;
    const long long rowbase = (long long)r * WW;

    if (tid < 4) {
        up[tid] = 0.f; ce[tid] = 0.f; dn[tid] = 0.f;
        up[1028 + tid] = 0.f; ce[1028 + tid] = 0.f; dn[1028 + tid] = 0.f;
    }

    // Staging: aligned float4 loads (coalesced), float4 LDS stores at
    // byte offset 16 + 16*tid (16B-aligned, uniform bank usage).
    float4 c4 = ((const float4*)(yp + rowbase))[tid];
    float4 u4 = make_float4(0.f, 0.f, 0.f, 0.f);
    float4 d4 = make_float4(0.f, 0.f, 0.f, 0.f);
    if (y >= 2)      u4 = ((const float4*)(yp + rowbase - 2 * WW))[tid];
    if (y < HH - 2)  d4 = ((const float4*)(yp + rowbase + 2 * WW))[tid];
    *(float4*)&ce[4 + x4] = c4;
    *(float4*)&up[4 + x4] = u4;
    *(float4*)&dn[4 + x4] = d4;
    __syncthreads();

    // Compute: strided assignment (x = tid + j*256) -> stride-1 LDS reads
    // across lanes (2 lanes/bank = conflict-free) and coalesced yt loads.
    float sum = 0.f;
#pragma unroll
    for (int j = 0; j < 4; ++j) {
        const int x   = tid + (j << 8);
        const int idx = 4 + x;
        const float c = ce[idx];
        const float t = yt[rowbase + x];

        float w = fabsf(c - up[idx - 2]);
        w = fmaxf(w, fabsf(c - up[idx]));
        w = fmaxf(w, fabsf(c - up[idx + 2]));
        w = fmaxf(w, fabsf(c - ce[idx - 2]));
        w = fmaxf(w, fabsf(c - ce[idx + 2]));
        w = fmaxf(w, fabsf(c - dn[idx - 2]));
        w = fmaxf(w, fabsf(c - dn[idx]));
        w = fmaxf(w, fabsf(c - dn[idx + 2]));

        // log1p(-c) == log(1-c) exactly in fp32 for c in [0.5,1) (Sterbenz),
        // and the -100 clamp covers c -> 1 / c == 0 (-inf).
        const float lp  = fmaxf(__logf(c), -100.f);
        const float l1p = fmaxf(__logf(1.f - c), -100.f);
        const float a   = -(t * lp + (1.f - t) * l1p);
        const float th  = (c >= 0.5f) ? c : 0.f;
        sum += w * th + a;
    }

    // Block reduction: wave shfl (64 lanes) -> LDS -> thread 0.
    for (int o = 32; o > 0; o >>= 1) sum += __shfl_down(sum, o);
    __shared__ float wsum[4];
    if ((tid & 63) == 0) wsum[tid >> 6] = sum;
    __syncthreads();
    if (tid == 0) partial[r] = wsum[0] + wsum[1] + wsum[2] + wsum[3];
}

// Single-block final reduction over 16384 partials; writes the mean.
__global__ __launch_bounds__(256) void closs_reduce(const float* __restrict__ partial,
                                                    float* __restrict__ out) {
    float s = 0.f;
    for (int i = threadIdx.x; i < NROWS; i += 256) s += partial[i];
    for (int o = 32; o > 0; o >>= 1) s += __shfl_down(s, o);
    __shared__ float wsum[4];
    if ((threadIdx.x & 63) == 0) wsum[threadIdx.x >> 6] = s;
    __syncthreads();
    if (threadIdx.x == 0)
        out[0] = (wsum[0] + wsum[1] + wsum[2] + wsum[3]) * (1.0f / (float)NELEM);
}

extern "C" void kernel_launch(void* const* d_in, const int* in_sizes, int n_in,
                              void* d_out, int out_size, void* d_ws, size_t ws_size,
                              hipStream_t stream) {
    const float* y_true = (const float*)d_in[0];
    const float* y_pred = (const float*)d_in[1];
    float* out = (float*)d_out;
    float* partial = (float*)d_ws;   // needs NROWS*4 = 64 KB of scratch

    closs_main<<<NROWS, 256, 0, stream>>>(y_true, y_pred, partial);
    closs_reduce<<<1, 256, 0, stream>>>(partial, out);
}

// Round 2
// 147.972 us; speedup vs baseline: 1.0997x; 1.0997x over previous
//
#include <hip/hip_runtime.h>

#define HH 1024
#define WW 1024
#define NB 16
#define NROWS (NB * HH)          // 16384 flat rows (b*H + y)
#define NELEM ((long long)NROWS * WW)

// One block per (b,y) row; thread tid handles x = 4*tid .. 4*tid+3.
// Stencil windows [x0-2 .. x0+5] for rows y-2, y, y+2 are read directly from
// global (unaligned float2/float4/float2) — neighbor re-reads hit L1/L2, so
// HBM fetch stays ~1x per input. No LDS staging, no barriers in the hot path.
__global__ __launch_bounds__(256) void closs_main(const float* __restrict__ yt,
                                                  const float* __restrict__ yp,
                                                  float* __restrict__ partial) {
    const int r   = blockIdx.x;         // flat row = b*H + y
    const int y   = r & (HH - 1);
    const int tid = threadIdx.x;
    const int x0  = tid << 2;
    const long long rowbase = (long long)r * WW;

    const bool has_up = (y >= 2);
    const bool has_dn = (y < HH - 2);
    const bool ledge  = (tid == 0);
    const bool redge  = (tid == 255);

    // Clamped window-load offsets (keep addresses in-bounds; edge lanes get
    // their pad-zeros patched in after the load).
    const int offL = ledge ? x0 : (x0 - 2);   // float2 covering x0-2, x0-1
    const int offR = redge ? x0 : (x0 + 4);   // float2 covering x0+4, x0+5

    const float* pce = yp + rowbase;
    const float* pup = pce - 2 * WW;
    const float* pdn = pce + 2 * WW;

    // Center row window w[k] <-> x0-2+k, k in [0,8)
    float ce[8];
    {
        float2 a = *(const float2*)(pce + offL);
        float4 b = *(const float4*)(pce + x0);
        float2 c = *(const float2*)(pce + offR);
        if (ledge) { a.x = 0.f; a.y = 0.f; }
        if (redge) { c.x = 0.f; c.y = 0.f; }
        ce[0]=a.x; ce[1]=a.y; ce[2]=b.x; ce[3]=b.y; ce[4]=b.z; ce[5]=b.w; ce[6]=c.x; ce[7]=c.y;
    }
    const float4 t4 = *(const float4*)(yt + rowbase + x0);

    // Running max |c - nb| over the 8 dilated neighbors; process up row, then
    // horizontal (ce), then dn row so only ~2 windows are live at once.
    float w0, w1, w2, w3;
    {
        // horizontal neighbors from ce window: element j center = ce[j+2],
        // left2 = ce[j], right2 = ce[j+4]
        w0 = fmaxf(fabsf(ce[2] - ce[0]), fabsf(ce[2] - ce[4]));
        w1 = fmaxf(fabsf(ce[3] - ce[1]), fabsf(ce[3] - ce[5]));
        w2 = fmaxf(fabsf(ce[4] - ce[2]), fabsf(ce[4] - ce[6]));
        w3 = fmaxf(fabsf(ce[5] - ce[3]), fabsf(ce[5] - ce[7]));
    }
    if (has_up) {   // wave-uniform branch
        float2 a = *(const float2*)(pup + offL);
        float4 b = *(const float4*)(pup + x0);
        float2 c = *(const float2*)(pup + offR);
        if (ledge) { a.x = 0.f; a.y = 0.f; }
        if (redge) { c.x = 0.f; c.y = 0.f; }
        float u[8] = {a.x, a.y, b.x, b.y, b.z, b.w, c.x, c.y};
        w0 = fmaxf(w0, fmaxf(fabsf(ce[2]-u[0]), fmaxf(fabsf(ce[2]-u[2]), fabsf(ce[2]-u[4]))));
        w1 = fmaxf(w1, fmaxf(fabsf(ce[3]-u[1]), fmaxf(fabsf(ce[3]-u[3]), fabsf(ce[3]-u[5]))));
        w2 = fmaxf(w2, fmaxf(fabsf(ce[4]-u[2]), fmaxf(fabsf(ce[4]-u[4]), fabsf(ce[4]-u[6]))));
        w3 = fmaxf(w3, fmaxf(fabsf(ce[5]-u[3]), fmaxf(fabsf(ce[5]-u[5]), fabsf(ce[5]-u[7]))));
    } else {        // up row is zero padding: |c - 0| = c (c >= 0 here, inputs are uniform[0,1))
        w0 = fmaxf(w0, fabsf(ce[2]));
        w1 = fmaxf(w1, fabsf(ce[3]));
        w2 = fmaxf(w2, fabsf(ce[4]));
        w3 = fmaxf(w3, fabsf(ce[5]));
    }
    if (has_dn) {
        float2 a = *(const float2*)(pdn + offL);
        float4 b = *(const float4*)(pdn + x0);
        float2 c = *(const float2*)(pdn + offR);
        if (ledge) { a.x = 0.f; a.y = 0.f; }
        if (redge) { c.x = 0.f; c.y = 0.f; }
        float d[8] = {a.x, a.y, b.x, b.y, b.z, b.w, c.x, c.y};
        w0 = fmaxf(w0, fmaxf(fabsf(ce[2]-d[0]), fmaxf(fabsf(ce[2]-d[2]), fabsf(ce[2]-d[4]))));
        w1 = fmaxf(w1, fmaxf(fabsf(ce[3]-d[1]), fmaxf(fabsf(ce[3]-d[3]), fabsf(ce[3]-d[5]))));
        w2 = fmaxf(w2, fmaxf(fabsf(ce[4]-d[2]), fmaxf(fabsf(ce[4]-d[4]), fabsf(ce[4]-d[6]))));
        w3 = fmaxf(w3, fmaxf(fabsf(ce[5]-d[3]), fmaxf(fabsf(ce[5]-d[5]), fabsf(ce[5]-d[7]))));
    } else {
        w0 = fmaxf(w0, fabsf(ce[2]));
        w1 = fmaxf(w1, fabsf(ce[3]));
        w2 = fmaxf(w2, fabsf(ce[4]));
        w3 = fmaxf(w3, fabsf(ce[5]));
    }

    // BCE + weighting. log1p(-c) == log(1-c) exactly in fp32 for c in [0.5,1)
    // (Sterbenz); the -100 clamp covers c -> 1 / c == 0.
    float sum = 0.f;
    const float cc[4] = {ce[2], ce[3], ce[4], ce[5]};
    const float tt[4] = {t4.x, t4.y, t4.z, t4.w};
    const float ww[4] = {w0, w1, w2, w3};
#pragma unroll
    for (int j = 0; j < 4; ++j) {
        const float c = cc[j];
        const float lp  = fmaxf(__logf(c), -100.f);
        const float l1p = fmaxf(__logf(1.f - c), -100.f);
        const float a   = -(tt[j] * lp + (1.f - tt[j]) * l1p);
        const float th  = (c >= 0.5f) ? c : 0.f;
        sum += ww[j] * th + a;
    }

    // Block reduction: wave shfl (64 lanes) -> LDS -> thread 0.
    for (int o = 32; o > 0; o >>= 1) sum += __shfl_down(sum, o);
    __shared__ float wsum[4];
    if ((tid & 63) == 0) wsum[tid >> 6] = sum;
    __syncthreads();
    if (tid == 0) partial[r] = wsum[0] + wsum[1] + wsum[2] + wsum[3];
}

// Final reduction over 16384 partials in one 1024-thread block; float4 loads
// give 4 independent in-flight loads per thread.
__global__ __launch_bounds__(1024) void closs_reduce(const float* __restrict__ partial,
                                                     float* __restrict__ out) {
    const float4* p4 = (const float4*)partial;   // 4096 float4s
    float s = 0.f;
#pragma unroll
    for (int i = 0; i < 4; ++i) {
        float4 v = p4[threadIdx.x + (i << 10)];
        s += (v.x + v.y) + (v.z + v.w);
    }
    for (int o = 32; o > 0; o >>= 1) s += __shfl_down(s, o);
    __shared__ float wsum[16];
    if ((threadIdx.x & 63) == 0) wsum[threadIdx.x >> 6] = s;
    __syncthreads();
    if (threadIdx.x == 0) {
        float t = 0.f;
#pragma unroll
        for (int i = 0; i < 16; ++i) t += wsum[i];
        out[0] = t * (1.0f / (float)NELEM);
    }
}

extern "C" void kernel_launch(void* const* d_in, const int* in_sizes, int n_in,
                              void* d_out, int out_size, void* d_ws, size_t ws_size,
                              hipStream_t stream) {
    const float* y_true = (const float*)d_in[0];
    const float* y_pred = (const float*)d_in[1];
    float* out = (float*)d_out;
    float* partial = (float*)d_ws;   // NROWS*4 = 64 KB scratch

    closs_main<<<NROWS, 256, 0, stream>>>(y_true, y_pred, partial);
    closs_reduce<<<1, 1024, 0, stream>>>(partial, out);
}

// Round 3
// 147.908 us; speedup vs baseline: 1.1002x; 1.0004x over previous
//
#include <hip/hip_runtime.h>

#define HH 1024
#define WW 1024
#define NB 16
#define KROWS 8                     // output rows per block (one parity, stride 2)
#define NELEM ((long long)NB * HH * WW)
// grid = NB images * 2 parities * (512/KROWS) segments = 16*2*64 = 2048 blocks

// Load the stencil window [x0-2 .. x0+5] of one yp row into w[8].
// Aligned float2/float4/float2 pieces; edge lanes patch their pad-zeros.
__device__ __forceinline__ void load_row(const float* __restrict__ rowp, int x0,
                                         bool ledge, bool redge,
                                         int offL, int offR, float w[8]) {
    float2 a = *(const float2*)(rowp + offL);
    float4 b = *(const float4*)(rowp + x0);
    float2 c = *(const float2*)(rowp + offR);
    if (ledge) { a.x = 0.f; a.y = 0.f; }
    if (redge) { c.x = 0.f; c.y = 0.f; }
    w[0]=a.x; w[1]=a.y; w[2]=b.x; w[3]=b.y; w[4]=b.z; w[5]=b.w; w[6]=c.x; w[7]=c.y;
}

__device__ __forceinline__ void zero_row(float w[8]) {
#pragma unroll
    for (int i = 0; i < 8; ++i) w[i] = 0.f;
}

__global__ __launch_bounds__(256) void closs_main(const float* __restrict__ yt,
                                                  const float* __restrict__ yp,
                                                  float* __restrict__ out) {
    const int bid = blockIdx.x;
    const int img = bid >> 7;          // 128 blocks per image
    const int rem = bid & 127;
    const int par = rem >> 6;          // parity 0/1
    const int seg = rem & 63;          // segment within parity plane
    const int y0  = seg * (2 * KROWS) + par;   // first output row (in-image)

    const int tid = threadIdx.x;
    const int x0  = tid << 2;
    const bool ledge = (tid == 0);
    const bool redge = (tid == 255);
    const int offL = ledge ? x0 : (x0 - 2);
    const int offR = redge ? x0 : (x0 + 4);

    const float* __restrict__ ybase = yp + (long long)img * (HH * WW);
    const float* __restrict__ tbase = yt + (long long)img * (HH * WW);

    // Rolling 3-row register window over one parity plane.
    float win[3][8];
    if (y0 >= 2) load_row(ybase + (y0 - 2) * WW, x0, ledge, redge, offL, offR, win[0]);
    else         zero_row(win[0]);
    load_row(ybase + y0 * WW, x0, ledge, redge, offL, offR, win[1]);

    float sum = 0.f;
#pragma unroll
    for (int k = 0; k < KROWS; ++k) {
        const int y = y0 + 2 * k;
        float* A = win[k % 3];           // row y-2
        float* B = win[(k + 1) % 3];     // row y
        float* C = win[(k + 2) % 3];     // row y+2
        if (y + 2 < HH) load_row(ybase + (y + 2) * WW, x0, ledge, redge, offL, offR, C);
        else            zero_row(C);

        const float4 t4 = *(const float4*)(tbase + y * WW + x0);
        const float tt[4] = {t4.x, t4.y, t4.z, t4.w};

#pragma unroll
        for (int j = 0; j < 4; ++j) {
            const float c = B[j + 2];
            // max|c-nb| over 8 dilated neighbors = max(max(nb)-c, c-min(nb));
            // fmax/fmin triples fold to v_max3/v_min3.
            float mx = fmaxf(fmaxf(A[j], A[j + 2]), A[j + 4]);
            mx = fmaxf(fmaxf(mx, B[j]), B[j + 4]);
            mx = fmaxf(fmaxf(mx, C[j]), C[j + 2]);
            mx = fmaxf(mx, C[j + 4]);
            float mn = fminf(fminf(A[j], A[j + 2]), A[j + 4]);
            mn = fminf(fminf(mn, B[j]), B[j + 4]);
            mn = fminf(fminf(mn, C[j]), C[j + 2]);
            mn = fminf(mn, C[j + 4]);
            const float w = fmaxf(mx - c, c - mn);

            // log1p(-c) == log(1-c) exactly in fp32 for c in [0.5,1) (Sterbenz);
            // the -100 clamp covers c -> 1 (log(0) = -inf) and c == 0.
            const float lp  = fmaxf(__logf(c), -100.f);
            const float l1p = fmaxf(__logf(1.f - c), -100.f);
            const float a   = -(tt[j] * lp + (1.f - tt[j]) * l1p);
            const float th  = (c >= 0.5f) ? c : 0.f;
            sum += w * th + a;
        }
    }

    // Block reduction: wave shfl (64 lanes) -> LDS -> one scaled atomicAdd.
    for (int o = 32; o > 0; o >>= 1) sum += __shfl_down(sum, o);
    __shared__ float wsum[4];
    if ((tid & 63) == 0) wsum[tid >> 6] = sum;
    __syncthreads();
    if (tid == 0) {
        const float total = wsum[0] + wsum[1] + wsum[2] + wsum[3];
        atomicAdd(out, total * (1.0f / (float)NELEM));
    }
}

extern "C" void kernel_launch(void* const* d_in, const int* in_sizes, int n_in,
                              void* d_out, int out_size, void* d_ws, size_t ws_size,
                              hipStream_t stream) {
    const float* y_true = (const float*)d_in[0];
    const float* y_pred = (const float*)d_in[1];
    float* out = (float*)d_out;

    // d_out is poisoned 0xAA before every launch; zero it for the atomics.
    hipMemsetAsync(out, 0, sizeof(float), stream);
    closs_main<<<NB * 2 * (HH / 2 / KROWS), 256, 0, stream>>>(y_true, y_pred, out);
}